// Round 10
// baseline (290.419 us; speedup 1.0000x reference)
//
#include <hip/hip_runtime.h>
#include <hip/hip_bf16.h>

typedef __attribute__((ext_vector_type(8)))  short bf16x8;   // 8 bf16 = 4 VGPRs
typedef __attribute__((ext_vector_type(16))) float f32x16;   // 32x32 MFMA accumulator

constexpr int Bn = 32, Cn = 64, Hn = 64, Wn = 256, On = 64, En = 4, Rn = 4;
constexpr float SCALE = 1.0f / Rn;

// packed-x geometry (round-1/7-verified layout): per (b,h) row, 258 slots x 128B,
// slot s holds c=0..63 of x[b][:][h][s-1], c-group cb at byte ((cb^(s&7))*16),
// slots 0 and 257 are zero (SAME-padding halo).
constexpr int ROW_B  = 258 * 128;   // 33024 B per packed row

constexpr int WTILE  = 64;          // w per conv block
constexpr int HSTRIP = 8;           // output rows per conv block
constexpr int SLOT_B = 66 * 128;    // 8448 B conv ring slot (slots w0..w0+65)
constexpr int NSLOT  = 6;           // 6-slot ring: 50.7 KB -> 3 blocks/CU

constexpr size_t WFRAG_B = 294912;
constexpr size_t XP_B    = (size_t)Bn * Hn * ROW_B;   // 67,633,152
constexpr size_t ZROW_B  = ROW_B;                     // zero row for h-OOB

#define GLOAD_LDS16(SRC, DST) \
    __builtin_amdgcn_global_load_lds( \
        (const __attribute__((address_space(1))) void*)(SRC), \
        (__attribute__((address_space(3))) void*)(DST), 16, 0, 0)

// ---------------------------------------------------------------------------
// Merge LoRA into conv weights (device helper, callable from fused prologue):
// Wfrag[e][mh][s][lane][j]:  o = mh*32 + (lane&31),
//   k: tap = s>>2, c = (s&3)*16 + (lane>>5)*8 + j
// ---------------------------------------------------------------------------
__device__ __forceinline__ void merge_body(
    int t, const float* __restrict__ Wc, const float* __restrict__ Wa,
    const float* __restrict__ Wb, __hip_bfloat16* __restrict__ Wfrag)
{
    int j    = t & 7;
    int lane = (t >> 3) & 63;
    int g    = t >> 9;                               // (e*2+mh)*36 + s
    int s    = g % 36;
    int mh   = (g / 36) & 1;
    int e    = g / 72;
    int m = lane & 31, half = lane >> 5;
    int o = mh * 32 + m;
    int tap = s >> 2, cq = s & 3;
    int c = cq * 16 + half * 8 + j;
    float acc = Wc[(o * Cn + c) * 9 + tap];
#pragma unroll
    for (int r = 0; r < Rn; ++r)
        acc += SCALE * Wb[(e * On + o) * Rn + r] * Wa[((e * Rn + r) * Cn + c) * 9 + tap];
    Wfrag[t] = __float2bfloat16(acc);
}

__global__ __launch_bounds__(256) void merge_k(
    const float* __restrict__ Wc, const float* __restrict__ Wa,
    const float* __restrict__ Wb, __hip_bfloat16* __restrict__ Wfrag)
{
    merge_body(blockIdx.x * 256 + threadIdx.x, Wc, Wa, Wb, Wfrag);
}

// ---------------------------------------------------------------------------
// Fused prologue: pack (round-8-verified bytes) + halo/zero-row + merge,
// one launch. Blocks: [0,4096) pack, [4096,4224) halo, [4224,4233) zero-row,
// [4233,4809) merge (576 blocks = 147456 threads exact).
// ---------------------------------------------------------------------------
__global__ __launch_bounds__(256) void prologue_k(
    const float* __restrict__ x, __hip_bfloat16* __restrict__ xp,
    __hip_bfloat16* __restrict__ zr,
    const float* __restrict__ Wc, const float* __restrict__ Wa,
    const float* __restrict__ Wb, __hip_bfloat16* __restrict__ Wfrag)
{
    const int blk = blockIdx.x;
    if (blk < 4096) {
        int l  = ((blk & 1) << 8) | threadIdx.x;     // 0..511 within row team
        int bh = blk >> 1;                           // b*64 + h
        int wLo = l & 3, cb = (l >> 2) & 7, wHi = l >> 5;
        int wq = wHi * 4 + wLo;                      // 0..63
        int b = bh >> 6, h = bh & 63;
        const float* src = x + (((size_t)(b * Cn + cb * 8) * Hn + h) * Wn) + 4 * wq;
        float4 f[8];
#pragma unroll
        for (int i = 0; i < 8; ++i)
            f[i] = *reinterpret_cast<const float4*>(src + (size_t)i * Hn * Wn);
        char* row = (char*)xp + (size_t)bh * ROW_B;
#pragma unroll
        for (int j = 0; j < 4; ++j) {
            union { __hip_bfloat16 u[8]; bf16x8 v; } pk;
#pragma unroll
            for (int i = 0; i < 8; ++i) {
                float v = (j == 0) ? f[i].x : (j == 1) ? f[i].y : (j == 2) ? f[i].z : f[i].w;
                pk.u[i] = __float2bfloat16(v);
            }
            int s = 4 * wq + 1 + j;                  // 1..256
            *reinterpret_cast<bf16x8*>(row + s * 128 + ((cb ^ (s & 7)) * 16)) = pk.v;
        }
    } else if (blk < 4096 + 128) {
        int z = (blk - 4096) * 256 + threadIdx.x;    // 0..32767
        int cb = z & 7, t = (z >> 3) & 1, bh = z >> 4;
        char* row = (char*)xp + (size_t)bh * ROW_B;
        bf16x8 zz = {};
        *reinterpret_cast<bf16x8*>(row + (t ? 257 : 0) * 128 + cb * 16) = zz;
    } else if (blk < 4096 + 128 + 9) {
        int t = (blk - 4096 - 128) * 256 + threadIdx.x;
        if (t < ROW_B / 16) {
            bf16x8 zz = {};
            reinterpret_cast<bf16x8*>(zr)[t] = zz;
        }
    } else {
        merge_body((blk - 4233) * 256 + threadIdx.x, Wc, Wa, Wb, Wfrag);
    }
}

// ---------------------------------------------------------------------------
// Fused conv, v12 = conv10 (best-measured structure: 1 row/iter, counted
// vmcnt(16), 16+3+16 = 35 max in flight < 63-entry vmcnt window) with:
//  * 6-slot ring (50.7 KB): 3 blocks/CU = 12 waves/CU (was 8 all session)
//  * prefetch lead 2: stage x-row st+3 at iter st, first read at compute(st+2)
//    -> DMA has 2 full barrier periods to land.
// Slot safety (slot(r) = (r+1) mod 6): iter st writes slot (st+4)%6; compute
// reads slots (st..st+2)%6 — disjoint. Overwritten slot held x-row st-3,
// last read at compute(st-2), >=2 barriers before the write. DMA->read:
// vmcnt(16) at end of iter st retires that iter's 3 DMAs (16 newest = stores),
// one barrier BEFORE the lead-2 deadline — extra slack, not less.
// ---------------------------------------------------------------------------
__global__ __launch_bounds__(256, 2) void conv12_k(
    const __hip_bfloat16* __restrict__ xp, const __hip_bfloat16* __restrict__ zr,
    const int* __restrict__ sid, const __hip_bfloat16* __restrict__ Wfrag,
    float* __restrict__ out)
{
    __shared__ __align__(16) char xs[NSLOT * SLOT_B];    // 50688 B ring

    // XCD-chunked bijective swizzle (1024 blocks, 1024%8==0)
    const int logical = ((blockIdx.x & 7) << 7) | (blockIdx.x >> 3);
    const int bx = logical & 3, by = (logical >> 2) & 7, b = logical >> 5;

    const int tid = threadIdx.x;
    const int w0  = bx * WTILE;
    const int h0  = by * HSTRIP;
    const int e   = sid[b];
    const size_t HW = (size_t)Hn * Wn;

    const int lane = tid & 63, wave = tid >> 6;
    const int mh = wave & 1, nh = wave >> 1;
    const int n = lane & 31, half = lane >> 5;

    // A fragments: 36 x bf16x8, loaded once (L2-resident), live in VGPRs/AGPRs.
    bf16x8 wf[36];
    const bf16x8* wg = reinterpret_cast<const bf16x8*>(Wfrag) + (size_t)(e * 2 + mh) * 36 * 64;
#pragma unroll
    for (int s = 0; s < 36; ++s) wf[s] = wg[s * 64 + lane];

    // window of packed row (b,gh) for this w-tile: slots w0..w0+65, contiguous
    const char* xpb = (const char*)xp + (size_t)b * Hn * ROW_B + (size_t)w0 * 128;
    const char* zrw = (const char*)zr + (size_t)w0 * 128;
    const int lofs = wave * 1024 + lane * 16;            // per-lane source offset

    auto m6 = [](int v) { return v >= NSLOT ? v - NSLOT : v; };  // v in [0,10]

    auto stage = [&](int rx) {                           // rx in [-1, 8]
        const int gh = h0 + rx;
        const char* src = ((unsigned)gh < (unsigned)Hn) ? (xpb + (size_t)gh * ROW_B) : zrw;
        char* dst = xs + m6(rx + 1) * SLOT_B + wave * 1024;   // wave-uniform dest
        GLOAD_LDS16(src + lofs,        dst);
        GLOAD_LDS16(src + 4096 + lofs, dst + 4096);
        GLOAD_LDS16(src + 4352 + lofs, dst + 4352);   // tail via benign overlap
    };

    // prologue: x rows h0-1 .. h0+2 -> slots 0..3 (full drain once)
    stage(-1); stage(0); stage(1); stage(2);
    asm volatile("s_waitcnt vmcnt(0) lgkmcnt(0)" ::: "memory");
    __builtin_amdgcn_s_barrier();

    for (int st = 0; st < HSTRIP; ++st) {
        // 1. DMA x-row st+3 (lead 2: first consumed at compute(st+2))
        if (st + 3 <= HSTRIP) stage(st + 3);
        asm volatile("" ::: "memory");   // pin DMA issue before epilogue stores

        // 2. compute output row h0+st (two independent acc chains)
        f32x16 a0, a1;
#pragma unroll
        for (int i = 0; i < 16; ++i) { a0[i] = 0.0f; a1[i] = 0.0f; }

#pragma unroll
        for (int s2 = 0; s2 < 18; ++s2) {
            {
                const int s = 2 * s2;
                const int tap = s >> 2, cq = s & 3;
                const int dh = tap / 3, dw = tap % 3;
                int ww = nh * 32 + n + dw;               // 0..65
                const char* p = xs + m6(st + dh) * SLOT_B
                              + ww * 128 + (((cq * 2 + half) ^ (ww & 7)) * 16);
                a0 = __builtin_amdgcn_mfma_f32_32x32x16_bf16(
                        wf[s], *reinterpret_cast<const bf16x8*>(p), a0, 0, 0, 0);
            }
            {
                const int s = 2 * s2 + 1;
                const int tap = s >> 2, cq = s & 3;
                const int dh = tap / 3, dw = tap % 3;
                int ww = nh * 32 + n + dw;
                const char* p = xs + m6(st + dh) * SLOT_B
                              + ww * 128 + (((cq * 2 + half) ^ (ww & 7)) * 16);
                a1 = __builtin_amdgcn_mfma_f32_32x32x16_bf16(
                        wf[s], *reinterpret_cast<const bf16x8*>(p), a1, 0, 0, 0);
            }
        }

        // 3. epilogue: direct global stores; lanes n=0..31 cover 128B contiguous
        //    at (o = mh*32 + 4*half + (r&3)+8*(r>>2), row hrow).
        {
            const int hrow = h0 + st;
            size_t base = ((size_t)(b * On + mh * 32 + 4 * half) * Hn + hrow) * Wn
                          + w0 + nh * 32 + n;
#pragma unroll
            for (int r = 0; r < 16; ++r) {
                int o_off = (r & 3) + 8 * (r >> 2);
                out[base + (size_t)o_off * HW] = a0[r] + a1[r];
            }
        }

        // 4. counted-vmcnt barrier: retire this iter's DMAs, keep the 16
        //    newest (this iter's stores) in flight across the barrier.
        asm volatile("s_waitcnt vmcnt(16) lgkmcnt(0)" ::: "memory");
        __builtin_amdgcn_s_barrier();
    }
}

// ---------------------------------------------------------------------------
// Fallback (ws too small): round-6 kernel verbatim (reg-staged, 101us).
// ---------------------------------------------------------------------------
constexpr int FB_WTILE  = 32;
constexpr int FB_HSTRIP = 16;
constexpr int FB_SLOT_B = 34 * 128;

__device__ __forceinline__ int fb_swz(int ww, int cb) {
    return ww * 128 + ((cb ^ ((ww >> 2) & 7)) * 16);
}

__global__ __launch_bounds__(128, 2) void conv8_k(
    const float* __restrict__ x, const int* __restrict__ sid,
    const __hip_bfloat16* __restrict__ Wfrag, float* __restrict__ out)
{
    __shared__ __align__(16) char xs[4 * FB_SLOT_B];

    const int tid = threadIdx.x;
    const int w0  = blockIdx.x * FB_WTILE;
    const int h0  = blockIdx.y * FB_HSTRIP;
    const int b   = blockIdx.z;
    const int e   = sid[b];
    const size_t HW = (size_t)Hn * Wn;

    const int lane = tid & 63, mh = tid >> 6;
    const int n = lane & 31, half = lane >> 5;

    bf16x8 wf[36];
    const bf16x8* wg = reinterpret_cast<const bf16x8*>(Wfrag) + (size_t)(e * 2 + mh) * 36 * 64;
#pragma unroll
    for (int s = 0; s < 36; ++s) wf[s] = wg[s * 64 + lane];

    const int pb = tid >> 3, q = tid & 7;
    const float* xbase = x + ((size_t)b * Cn + pb * 4) * HW + w0 + 4 * q;

    const int hside = tid >> 6, hc = tid & 63;
    const int gwh   = hside ? (w0 + FB_WTILE) : (w0 - 1);
    const bool hv   = (unsigned)gwh < (unsigned)Wn;
    const float* hbase = x + ((size_t)b * Cn + hc) * HW + gwh;

    auto stage_load = [&](float4 (&f)[4], float& hx, int rx) {
        const int gh = h0 + rx;
        if ((unsigned)gh < (unsigned)Hn) {
            const float* src = xbase + (size_t)gh * Wn;
#pragma unroll
            for (int r = 0; r < 4; ++r)
                f[r] = *reinterpret_cast<const float4*>(src + r * HW);
            hx = hv ? hbase[(size_t)gh * Wn] : 0.0f;
        } else {
            float4 z4 = make_float4(0.0f, 0.0f, 0.0f, 0.0f);
#pragma unroll
            for (int r = 0; r < 4; ++r) f[r] = z4;
            hx = 0.0f;
        }
    };
    auto stage_store = [&](float4 (&f)[4], float& hx, int rx) {
        const int slot = (rx + 1) & 3;
        char* dbase = xs + slot * FB_SLOT_B;
        const int cb = pb >> 1, sub = (pb & 1) * 8;
#pragma unroll
        for (int j = 0; j < 4; ++j) {
            union { __hip_bfloat16 u[4]; short4 v; } pk;
#pragma unroll
            for (int r = 0; r < 4; ++r) {
                float v = (j == 0) ? f[r].x : (j == 1) ? f[r].y : (j == 2) ? f[r].z : f[r].w;
                pk.u[r] = __float2bfloat16(v);
            }
            int ww = 4 * q + 1 + j;
            *reinterpret_cast<short4*>(dbase + fb_swz(ww, cb) + sub) = pk.v;
        }
        {
            __hip_bfloat16 hb = __float2bfloat16(hx);
            int ww = hside ? (FB_WTILE + 1) : 0;
            *reinterpret_cast<__hip_bfloat16*>(dbase + fb_swz(ww, hc >> 3) + (hc & 7) * 2) = hb;
        }
    };

    auto barrier = [&]() {
        asm volatile("s_waitcnt lgkmcnt(0)" ::: "memory");
        __builtin_amdgcn_s_barrier();
    };

    float4 fA[4], fB[4];
    float  hxA, hxB;

    stage_load(fA, hxA, -1); stage_store(fA, hxA, -1);
    stage_load(fA, hxA, 0);  stage_store(fA, hxA, 0);
    stage_load(fA, hxA, 1);  stage_store(fA, hxA, 1);
    stage_load(fA, hxA, 2);
    barrier();

    for (int st = 0; st < FB_HSTRIP; ++st) {
        const bool do_issue = (st + 3 <= FB_HSTRIP);
        if (do_issue) {
            if (st & 1) stage_load(fA, hxA, st + 3);
            else        stage_load(fB, hxB, st + 3);
        }

        f32x16 a;
#pragma unroll
        for (int i = 0; i < 16; ++i) a[i] = 0.0f;

#pragma unroll
        for (int s = 0; s < 36; ++s) {
            const int tap = s >> 2, cq = s & 3;
            const int dh = tap / 3, dw = tap % 3;
            const int slotbase = ((st + dh) & 3) * FB_SLOT_B;
            int ww = n + dw;
            bf16x8 bf = *reinterpret_cast<const bf16x8*>(xs + slotbase + fb_swz(ww, cq * 2 + half));
            a = __builtin_amdgcn_mfma_f32_32x32x16_bf16(wf[s], bf, a, 0, 0, 0);
        }

        const bool do_store = (st + 2 <= FB_HSTRIP);
        if (do_store) {
            if (st & 1) stage_store(fB, hxB, st + 2);
            else        stage_store(fA, hxA, st + 2);
        }

        {
            const int hrow = h0 + st;
            size_t base = ((size_t)(b * On + mh * 32 + 4 * half) * Hn + hrow) * Wn + w0 + n;
#pragma unroll
            for (int r = 0; r < 16; ++r) {
                int o_off = (r & 3) + 8 * (r >> 2);
                out[base + (size_t)o_off * HW] = a[r];
            }
        }

        barrier();
    }
}

// ---------------------------------------------------------------------------
extern "C" void kernel_launch(void* const* d_in, const int* in_sizes, int n_in,
                              void* d_out, int out_size, void* d_ws, size_t ws_size,
                              hipStream_t stream)
{
    const float* x   = (const float*)d_in[0];
    const int*   sid = (const int*)d_in[1];
    const float* Wc  = (const float*)d_in[2];
    const float* Wa  = (const float*)d_in[3];
    const float* Wb  = (const float*)d_in[4];
    float*       out = (float*)d_out;

    __hip_bfloat16* Wfrag = (__hip_bfloat16*)d_ws;

    const size_t NEED = WFRAG_B + XP_B + ZROW_B;   // 67,961,088
    if (ws_size >= NEED) {
        __hip_bfloat16* xp = (__hip_bfloat16*)((char*)d_ws + WFRAG_B);
        __hip_bfloat16* zw = (__hip_bfloat16*)((char*)d_ws + WFRAG_B + XP_B);
        prologue_k<<<4096 + 128 + 9 + 576, 256, 0, stream>>>(x, xp, zw, Wc, Wa, Wb, Wfrag);
        conv12_k<<<dim3(1024, 1, 1), 256, 0, stream>>>(xp, zw, sid, Wfrag, out);
    } else {
        merge_k<<<En * 2 * 36 * 64 * 8 / 256, 256, 0, stream>>>(Wc, Wa, Wb, Wfrag);
        dim3 grid(Wn / FB_WTILE, Hn / FB_HSTRIP, Bn);
        conv8_k<<<grid, 128, 0, stream>>>(x, sid, Wfrag, out);
    }
}

// Round 11
// 279.548 us; speedup vs baseline: 1.0389x; 1.0389x over previous
//
#include <hip/hip_runtime.h>
#include <hip/hip_bf16.h>

typedef __attribute__((ext_vector_type(8)))  short bf16x8;   // 8 bf16 = 4 VGPRs
typedef __attribute__((ext_vector_type(16))) float f32x16;   // 32x32 MFMA accumulator

constexpr int Bn = 32, Cn = 64, Hn = 64, Wn = 256, On = 64, En = 4, Rn = 4;
constexpr float SCALE = 1.0f / Rn;

// packed-x geometry (round-1/7-verified layout): per (b,h) row, 258 slots x 128B,
// slot s holds c=0..63 of x[b][:][h][s-1], c-group cb at byte ((cb^(s&7))*16),
// slots 0 and 257 are zero (SAME-padding halo).
constexpr int ROW_B  = 258 * 128;   // 33024 B per packed row

constexpr int WTILE  = 64;          // w per conv block
constexpr int HSTRIP = 8;           // output rows per conv block
constexpr int SLOT_B = 66 * 128;    // 8448 B conv ring slot (slots w0..w0+65)
constexpr int PB_STR = 80;          // pbuf per-lane stride (bytes): 16-aligned,
                                    // lane l -> bank (l*20)%32 covers 8 distinct
                                    // banks per 8-lane b128 phase -> conflict-free

constexpr size_t WFRAG_B = 294912;
constexpr size_t XP_B    = (size_t)Bn * Hn * ROW_B;   // 67,633,152
constexpr size_t ZROW_B  = ROW_B;                     // zero row for h-OOB

#define GLOAD_LDS16(SRC, DST) \
    __builtin_amdgcn_global_load_lds( \
        (const __attribute__((address_space(1))) void*)(SRC), \
        (__attribute__((address_space(3))) void*)(DST), 16, 0, 0)

// ---------------------------------------------------------------------------
// Merge LoRA into conv weights, in 32x32x16 A-fragment order (unchanged):
// Wfrag[e][mh][s][lane][j]:  o = mh*32 + (lane&31),
//   k: tap = s>>2, c = (s&3)*16 + (lane>>5)*8 + j
// ---------------------------------------------------------------------------
__global__ __launch_bounds__(256) void merge_k(
    const float* __restrict__ Wc, const float* __restrict__ Wa,
    const float* __restrict__ Wb, __hip_bfloat16* __restrict__ Wfrag)
{
    int t = blockIdx.x * 256 + threadIdx.x;          // 0..147455 exact
    int j    = t & 7;
    int lane = (t >> 3) & 63;
    int g    = t >> 9;                               // (e*2+mh)*36 + s
    int s    = g % 36;
    int mh   = (g / 36) & 1;
    int e    = g / 72;
    int m = lane & 31, half = lane >> 5;
    int o = mh * 32 + m;
    int tap = s >> 2, cq = s & 3;
    int c = cq * 16 + half * 8 + j;
    float acc = Wc[(o * Cn + c) * 9 + tap];
#pragma unroll
    for (int r = 0; r < Rn; ++r)
        acc += SCALE * Wb[(e * On + o) * Rn + r] * Wa[((e * Rn + r) * Cn + c) * 9 + tap];
    Wfrag[t] = __float2bfloat16(acc);
}

// ---------------------------------------------------------------------------
// Pack pass (round-8-verified bytes): x fp32 NCHW -> xp bf16 ring-image rows.
// ---------------------------------------------------------------------------
__global__ __launch_bounds__(256) void pack2_k(
    const float* __restrict__ x, __hip_bfloat16* __restrict__ xp,
    __hip_bfloat16* __restrict__ zr)
{
    const int blk = blockIdx.x;
    if (blk < 4096) {
        int l  = ((blk & 1) << 8) | threadIdx.x;     // 0..511 within row team
        int bh = blk >> 1;                           // b*64 + h
        int wLo = l & 3, cb = (l >> 2) & 7, wHi = l >> 5;
        int wq = wHi * 4 + wLo;                      // 0..63
        int b = bh >> 6, h = bh & 63;
        const float* src = x + (((size_t)(b * Cn + cb * 8) * Hn + h) * Wn) + 4 * wq;
        float4 f[8];
#pragma unroll
        for (int i = 0; i < 8; ++i)
            f[i] = *reinterpret_cast<const float4*>(src + (size_t)i * Hn * Wn);
        char* row = (char*)xp + (size_t)bh * ROW_B;
#pragma unroll
        for (int j = 0; j < 4; ++j) {
            union { __hip_bfloat16 u[8]; bf16x8 v; } pk;
#pragma unroll
            for (int i = 0; i < 8; ++i) {
                float v = (j == 0) ? f[i].x : (j == 1) ? f[i].y : (j == 2) ? f[i].z : f[i].w;
                pk.u[i] = __float2bfloat16(v);
            }
            int s = 4 * wq + 1 + j;                  // 1..256
            *reinterpret_cast<bf16x8*>(row + s * 128 + ((cb ^ (s & 7)) * 16)) = pk.v;
        }
    } else if (blk < 4096 + 128) {
        int z = (blk - 4096) * 256 + threadIdx.x;    // 0..32767
        int cb = z & 7, t = (z >> 3) & 1, bh = z >> 4;
        char* row = (char*)xp + (size_t)bh * ROW_B;
        bf16x8 zz = {};
        *reinterpret_cast<bf16x8*>(row + (t ? 257 : 0) * 128 + cb * 16) = zz;
    } else {
        int t = (blk - 4096 - 128) * 256 + threadIdx.x;
        if (t < ROW_B / 16) {
            bf16x8 zz = {};
            reinterpret_cast<bf16x8*>(zr)[t] = zz;
        }
    }
}

// ---------------------------------------------------------------------------
// Fused conv, v13: split-C for occupancy. 512 threads = 8 waves
// (mh, nh, kh); wave kh owns c-quads {2kh, 2kh+1} -> wf[18] = 72 VGPRs
// (was 144) -> target <=128 VGPR/wave -> 4 waves/SIMD = 16 waves/CU
// (2x the 8-wave cap every prior round was stuck at).
// kh0 waves: conv10's exact verified pattern (3 DMA via global_load_lds,
// 18 ds_read+MFMA, pbuf-combine, 16 stores, vmcnt(16) counted barrier).
// kh1 waves: 18 ds_read+MFMA, write partial f32x16 to pbuf (stride 80B,
// conflict-free), no global traffic, lgkmcnt-only barriers.
// Two barriers/iter: (A) pbuf publish, (B) ring publish + pbuf reuse.
// Per-block totals unchanged vs conv10: 144 ds_read + 144 MFMA per row.
// ---------------------------------------------------------------------------
__global__ __launch_bounds__(512, 4) void conv13_k(
    const __hip_bfloat16* __restrict__ xp, const __hip_bfloat16* __restrict__ zr,
    const int* __restrict__ sid, const __hip_bfloat16* __restrict__ Wfrag,
    float* __restrict__ out)
{
    __shared__ __align__(16) char xs[4 * SLOT_B];            // 33792 B ring
    __shared__ __align__(16) char pbuf[4 * 64 * PB_STR];     // 20480 B partials

    // XCD-chunked bijective swizzle (1024 blocks, 1024%8==0)
    const int logical = ((blockIdx.x & 7) << 7) | (blockIdx.x >> 3);
    const int bx = logical & 3, by = (logical >> 2) & 7, b = logical >> 5;

    const int tid = threadIdx.x;                             // 0..511
    const int w0  = bx * WTILE;
    const int h0  = by * HSTRIP;
    const int e   = sid[b];
    const size_t HW = (size_t)Hn * Wn;

    const int lane = tid & 63, wave = tid >> 6;              // wave 0..7
    const int mh = wave & 1, nh = (wave >> 1) & 1, kh = wave >> 2;
    const int n = lane & 31, half = lane >> 5;

    // A fragments: 18 x bf16x8 (this wave's c-half), live in VGPRs/AGPRs.
    // Wfrag s-index = tap*4 + (kh*2 + cqq).
    bf16x8 wf[18];
    const bf16x8* wg = reinterpret_cast<const bf16x8*>(Wfrag) + (size_t)(e * 2 + mh) * 36 * 64;
#pragma unroll
    for (int tap = 0; tap < 9; ++tap)
#pragma unroll
        for (int cqq = 0; cqq < 2; ++cqq)
            wf[tap * 2 + cqq] = wg[(tap * 4 + kh * 2 + cqq) * 64 + lane];

    // window of packed row (b,gh) for this w-tile: slots w0..w0+65, contiguous
    const char* xpb = (const char*)xp + (size_t)b * Hn * ROW_B + (size_t)w0 * 128;
    const char* zrw = (const char*)zr + (size_t)w0 * 128;
    const int lofs = wave * 1024 + lane * 16;    // kh0 waves (0..3) cover 4096 B

    auto stage = [&](int rx) {                   // called by kh==0 waves only
        const int gh = h0 + rx;
        const char* src = ((unsigned)gh < (unsigned)Hn) ? (xpb + (size_t)gh * ROW_B) : zrw;
        char* dst = xs + ((rx + 1) & 3) * SLOT_B + wave * 1024;   // wave-uniform dest
        GLOAD_LDS16(src + lofs,        dst);
        GLOAD_LDS16(src + 4096 + lofs, dst + 4096);
        GLOAD_LDS16(src + 4352 + lofs, dst + 4352);   // tail via benign overlap
    };

    char* pb = pbuf + ((wave & 3) * 64 + lane) * PB_STR;     // pair-shared slot

    // prologue: x rows h0-1, h0, h0+1 -> slots 0,1,2
    if (kh == 0) {
        stage(-1); stage(0); stage(1);
        asm volatile("s_waitcnt vmcnt(0) lgkmcnt(0)" ::: "memory");
    }
    __builtin_amdgcn_s_barrier();

    for (int st = 0; st < HSTRIP; ++st) {
        // 1. DMA next x-row (slot (st+3)&3; disjoint from read slots st..st+2;
        //    its previous reader finished at compute(st-1), before last barrier)
        if (kh == 0) stage(st + 2);
        asm volatile("" ::: "memory");   // pin DMA issue before later stores

        // 2. compute partial for output row h0+st over this wave's c-half
        f32x16 a;
#pragma unroll
        for (int i = 0; i < 16; ++i) a[i] = 0.0f;

#pragma unroll
        for (int tap = 0; tap < 9; ++tap) {
            const int dh = tap / 3, dw = tap % 3;
            const int slotbase = ((st + dh) & 3) * SLOT_B;
            const int ww = nh * 32 + n + dw;                 // 0..65
            const char* pbase = xs + slotbase + ww * 128;
#pragma unroll
            for (int cqq = 0; cqq < 2; ++cqq) {
                const int cg = (kh * 2 + cqq) * 2 + half;    // c-group 0..7
                bf16x8 bf = *reinterpret_cast<const bf16x8*>(
                    pbase + ((cg ^ (ww & 7)) * 16));
                a = __builtin_amdgcn_mfma_f32_32x32x16_bf16(wf[tap * 2 + cqq], bf, a, 0, 0, 0);
            }
        }

        // 3. kh1 publishes its partial to pbuf
        if (kh == 1) {
#pragma unroll
            for (int k = 0; k < 4; ++k) {
                float4 v = make_float4(a[4 * k + 0], a[4 * k + 1], a[4 * k + 2], a[4 * k + 3]);
                *reinterpret_cast<float4*>(pb + k * 16) = v;
            }
        }
        asm volatile("s_waitcnt lgkmcnt(0)" ::: "memory");   // pbuf visible
        __builtin_amdgcn_s_barrier();                        // barrier A

        // 4. kh0 combines + stores; lanes n=0..31 cover 128B contiguous at
        //    (o = mh*32 + 4*half + (r&3)+8*(r>>2), row hrow).
        if (kh == 0) {
            const int hrow = h0 + st;
            size_t base = ((size_t)(b * On + mh * 32 + 4 * half) * Hn + hrow) * Wn
                          + w0 + nh * 32 + n;
#pragma unroll
            for (int k = 0; k < 4; ++k) {
                float4 p = *reinterpret_cast<const float4*>(pb + k * 16);
#pragma unroll
                for (int q = 0; q < 4; ++q) {
                    int r = 4 * k + q;
                    int o_off = (r & 3) + 8 * (r >> 2);
                    float pv = (q == 0) ? p.x : (q == 1) ? p.y : (q == 2) ? p.z : p.w;
                    out[base + (size_t)o_off * HW] = a[r] + pv;
                }
            }
            // counted vmcnt: retire this iter's 3 DMAs, keep the 16 newest
            // (this iter's stores) in flight. Max in flight 16+3+16=35 < 63.
            asm volatile("s_waitcnt vmcnt(16) lgkmcnt(0)" ::: "memory");
        } else {
            asm volatile("s_waitcnt lgkmcnt(0)" ::: "memory");
        }
        __builtin_amdgcn_s_barrier();                        // barrier B
    }
}

// ---------------------------------------------------------------------------
// Fallback (ws too small): round-6 kernel verbatim (reg-staged, 101us).
// ---------------------------------------------------------------------------
constexpr int FB_WTILE  = 32;
constexpr int FB_HSTRIP = 16;
constexpr int FB_SLOT_B = 34 * 128;

__device__ __forceinline__ int fb_swz(int ww, int cb) {
    return ww * 128 + ((cb ^ ((ww >> 2) & 7)) * 16);
}

__global__ __launch_bounds__(128, 2) void conv8_k(
    const float* __restrict__ x, const int* __restrict__ sid,
    const __hip_bfloat16* __restrict__ Wfrag, float* __restrict__ out)
{
    __shared__ __align__(16) char xs[4 * FB_SLOT_B];

    const int tid = threadIdx.x;
    const int w0  = blockIdx.x * FB_WTILE;
    const int h0  = blockIdx.y * FB_HSTRIP;
    const int b   = blockIdx.z;
    const int e   = sid[b];
    const size_t HW = (size_t)Hn * Wn;

    const int lane = tid & 63, mh = tid >> 6;
    const int n = lane & 31, half = lane >> 5;

    bf16x8 wf[36];
    const bf16x8* wg = reinterpret_cast<const bf16x8*>(Wfrag) + (size_t)(e * 2 + mh) * 36 * 64;
#pragma unroll
    for (int s = 0; s < 36; ++s) wf[s] = wg[s * 64 + lane];

    const int pb = tid >> 3, q = tid & 7;
    const float* xbase = x + ((size_t)b * Cn + pb * 4) * HW + w0 + 4 * q;

    const int hside = tid >> 6, hc = tid & 63;
    const int gwh   = hside ? (w0 + FB_WTILE) : (w0 - 1);
    const bool hv   = (unsigned)gwh < (unsigned)Wn;
    const float* hbase = x + ((size_t)b * Cn + hc) * HW + gwh;

    auto stage_load = [&](float4 (&f)[4], float& hx, int rx) {
        const int gh = h0 + rx;
        if ((unsigned)gh < (unsigned)Hn) {
            const float* src = xbase + (size_t)gh * Wn;
#pragma unroll
            for (int r = 0; r < 4; ++r)
                f[r] = *reinterpret_cast<const float4*>(src + r * HW);
            hx = hv ? hbase[(size_t)gh * Wn] : 0.0f;
        } else {
            float4 z4 = make_float4(0.0f, 0.0f, 0.0f, 0.0f);
#pragma unroll
            for (int r = 0; r < 4; ++r) f[r] = z4;
            hx = 0.0f;
        }
    };
    auto stage_store = [&](float4 (&f)[4], float& hx, int rx) {
        const int slot = (rx + 1) & 3;
        char* dbase = xs + slot * FB_SLOT_B;
        const int cb = pb >> 1, sub = (pb & 1) * 8;
#pragma unroll
        for (int j = 0; j < 4; ++j) {
            union { __hip_bfloat16 u[4]; short4 v; } pk;
#pragma unroll
            for (int r = 0; r < 4; ++r) {
                float v = (j == 0) ? f[r].x : (j == 1) ? f[r].y : (j == 2) ? f[r].z : f[r].w;
                pk.u[r] = __float2bfloat16(v);
            }
            int ww = 4 * q + 1 + j;
            *reinterpret_cast<short4*>(dbase + fb_swz(ww, cb) + sub) = pk.v;
        }
        {
            __hip_bfloat16 hb = __float2bfloat16(hx);
            int ww = hside ? (FB_WTILE + 1) : 0;
            *reinterpret_cast<__hip_bfloat16*>(dbase + fb_swz(ww, hc >> 3) + (hc & 7) * 2) = hb;
        }
    };

    auto barrier = [&]() {
        asm volatile("s_waitcnt lgkmcnt(0)" ::: "memory");
        __builtin_amdgcn_s_barrier();
    };

    float4 fA[4], fB[4];
    float  hxA, hxB;

    stage_load(fA, hxA, -1); stage_store(fA, hxA, -1);
    stage_load(fA, hxA, 0);  stage_store(fA, hxA, 0);
    stage_load(fA, hxA, 1);  stage_store(fA, hxA, 1);
    stage_load(fA, hxA, 2);
    barrier();

    for (int st = 0; st < FB_HSTRIP; ++st) {
        const bool do_issue = (st + 3 <= FB_HSTRIP);
        if (do_issue) {
            if (st & 1) stage_load(fA, hxA, st + 3);
            else        stage_load(fB, hxB, st + 3);
        }

        f32x16 a;
#pragma unroll
        for (int i = 0; i < 16; ++i) a[i] = 0.0f;

#pragma unroll
        for (int s = 0; s < 36; ++s) {
            const int tap = s >> 2, cq = s & 3;
            const int dh = tap / 3, dw = tap % 3;
            const int slotbase = ((st + dh) & 3) * FB_SLOT_B;
            int ww = n + dw;
            bf16x8 bf = *reinterpret_cast<const bf16x8*>(xs + slotbase + fb_swz(ww, cq * 2 + half));
            a = __builtin_amdgcn_mfma_f32_32x32x16_bf16(wf[s], bf, a, 0, 0, 0);
        }

        const bool do_store = (st + 2 <= FB_HSTRIP);
        if (do_store) {
            if (st & 1) stage_store(fB, hxB, st + 2);
            else        stage_store(fA, hxA, st + 2);
        }

        {
            const int hrow = h0 + st;
            size_t base = ((size_t)(b * On + mh * 32 + 4 * half) * Hn + hrow) * Wn + w0 + n;
#pragma unroll
            for (int r = 0; r < 16; ++r) {
                int o_off = (r & 3) + 8 * (r >> 2);
                out[base + (size_t)o_off * HW] = a[r];
            }
        }

        barrier();
    }
}

// ---------------------------------------------------------------------------
extern "C" void kernel_launch(void* const* d_in, const int* in_sizes, int n_in,
                              void* d_out, int out_size, void* d_ws, size_t ws_size,
                              hipStream_t stream)
{
    const float* x   = (const float*)d_in[0];
    const int*   sid = (const int*)d_in[1];
    const float* Wc  = (const float*)d_in[2];
    const float* Wa  = (const float*)d_in[3];
    const float* Wb  = (const float*)d_in[4];
    float*       out = (float*)d_out;

    __hip_bfloat16* Wfrag = (__hip_bfloat16*)d_ws;

    merge_k<<<En * 2 * 36 * 64 * 8 / 256, 256, 0, stream>>>(Wc, Wa, Wb, Wfrag);

    const size_t NEED = WFRAG_B + XP_B + ZROW_B;   // 67,961,088
    if (ws_size >= NEED) {
        __hip_bfloat16* xp = (__hip_bfloat16*)((char*)d_ws + WFRAG_B);
        __hip_bfloat16* zw = (__hip_bfloat16*)((char*)d_ws + WFRAG_B + XP_B);
        pack2_k<<<4096 + 128 + 9, 256, 0, stream>>>(x, xp, zw);
        conv13_k<<<dim3(1024, 1, 1), 512, 0, stream>>>(xp, zw, sid, Wfrag, out);
    } else {
        dim3 grid(Wn / FB_WTILE, Hn / FB_HSTRIP, Bn);
        conv8_k<<<grid, 128, 0, stream>>>(x, sid, Wfrag, out);
    }
}

// Round 12
// 269.640 us; speedup vs baseline: 1.0771x; 1.0367x over previous
//
#include <hip/hip_runtime.h>
#include <hip/hip_bf16.h>

typedef __attribute__((ext_vector_type(8)))  short bf16x8;   // 8 bf16 = 4 VGPRs
typedef __attribute__((ext_vector_type(16))) float f32x16;   // 32x32 MFMA accumulator

constexpr int Bn = 32, Cn = 64, Hn = 64, Wn = 256, On = 64, En = 4, Rn = 4;
constexpr float SCALE = 1.0f / Rn;

constexpr int WTILE  = 128;         // w per block
constexpr int HSTRIP = 8;           // output rows per block
constexpr int SLOT_B = 130 * 128;   // bytes per x-row ring slot (130 ww x 64 c x 2B)

// Ring swizzle: 16B group of c-block cb in slot ww sits at byte
//   ww*128 + ((cb ^ ((ww>>2)&7)) * 16)
// Writes (lane q -> ww=4q+1+j): (ww>>2)&7 = (q+k)&7 spreads 8 groups -> conflict-free.
// Reads (lane n -> ww=base+n):   4 consecutive n share a group x8 groups x2 halves
//   = 8 lanes/group = b128 minimum.
__device__ __forceinline__ int swz(int ww, int cb) {
    return ww * 128 + ((cb ^ ((ww >> 2) & 7)) * 16);
}

// ---------------------------------------------------------------------------
// Merge LoRA into conv weights, in 32x32x16 A-fragment order:
// Wfrag[e][mh][s][lane][j]:  o = mh*32 + (lane&31),
//   k: tap = s>>2, c = (s&3)*16 + (lane>>5)*8 + j
// ---------------------------------------------------------------------------
__global__ __launch_bounds__(256) void merge_k(
    const float* __restrict__ Wc, const float* __restrict__ Wa,
    const float* __restrict__ Wb, __hip_bfloat16* __restrict__ Wfrag)
{
    int t = blockIdx.x * 256 + threadIdx.x;          // 0..147455 exact
    int j    = t & 7;
    int lane = (t >> 3) & 63;
    int g    = t >> 9;                               // (e*2+mh)*36 + s
    int s    = g % 36;
    int mh   = (g / 36) & 1;
    int e    = g / 72;
    int m = lane & 31, half = lane >> 5;
    int o = mh * 32 + m;
    int tap = s >> 2, cq = s & 3;
    int c = cq * 16 + half * 8 + j;
    float acc = Wc[(o * Cn + c) * 9 + tap];
#pragma unroll
    for (int r = 0; r < Rn; ++r)
        acc += SCALE * Wb[(e * On + o) * Rn + r] * Wa[((e * Rn + r) * Cn + c) * 9 + tap];
    Wfrag[t] = __float2bfloat16(acc);
}

// ---------------------------------------------------------------------------
// Fused conv (session-best, round-4-verified 270.4us):
//   [loads(st+2) | compute(st) | stage_store(st+2) | out-stores(st) | barrier]
// Reg-staged fp32->bf16 pack, (ww>>2)&7 swizzle, direct global stores,
// lgkmcnt-only barrier (out-stores and staged loads float across).
// ---------------------------------------------------------------------------
__global__ __launch_bounds__(256, 2) void conv5_k(
    const float* __restrict__ x, const int* __restrict__ sid,
    const __hip_bfloat16* __restrict__ Wfrag, float* __restrict__ out)
{
    __shared__ __align__(16) char xs[4 * SLOT_B];        // 66560 B ring

    const int tid = threadIdx.x;
    const int w0  = blockIdx.x * WTILE;
    const int h0  = blockIdx.y * HSTRIP;
    const int b   = blockIdx.z;
    const int e   = sid[b];
    const size_t HW = (size_t)Hn * Wn;

    const int lane = tid & 63, wave = tid >> 6;
    const int mh = wave & 1, nh = wave >> 1;
    const int n = lane & 31, half = lane >> 5;

    // A fragments: 36 x bf16x8, loaded once (L2-resident), live in VGPRs/AGPRs.
    bf16x8 wf[36];
    const bf16x8* wg = reinterpret_cast<const bf16x8*>(Wfrag) + (size_t)(e * 2 + mh) * 36 * 64;
#pragma unroll
    for (int s = 0; s < 36; ++s) wf[s] = wg[s * 64 + lane];

    // --- staging thread mapping: thread = (cb = tid>>5, w-quad q = tid&31) ---
    const int cb = tid >> 5;                 // c-group 0..7
    const int q  = tid & 31;                 // w-quad 0..31
    const float* xbase = x + ((size_t)b * Cn + cb * 8) * HW + w0 + 4 * q;

    // halo mapping: 32 threads, 4 c each, ds_write_b64
    const int hside = tid >> 4;              // tid<32: 0=left (gw=w0-1), 1=right
    const int hidx  = tid & 15;
    const int hcb   = hidx >> 1, hhi = hidx & 1;
    const int gwh   = hside ? (w0 + WTILE) : (w0 - 1);
    const bool hv   = (unsigned)gwh < (unsigned)Wn;
    const float* hbase = x + ((size_t)b * Cn + hcb * 8 + hhi * 4) * HW + gwh;

    float4 f[8];
    float  hx[4];

    auto stage_load = [&](int rx) {
        const int gh = h0 + rx;
        if ((unsigned)gh < (unsigned)Hn) {
            const float* src = xbase + (size_t)gh * Wn;
#pragma unroll
            for (int r = 0; r < 8; ++r)
                f[r] = *reinterpret_cast<const float4*>(src + r * HW);
            if (tid < 32) {
                if (hv) {
                    const float* hs = hbase + (size_t)gh * Wn;
#pragma unroll
                    for (int i = 0; i < 4; ++i) hx[i] = hs[i * HW];
                } else {
#pragma unroll
                    for (int i = 0; i < 4; ++i) hx[i] = 0.0f;
                }
            }
        } else {
            float4 z4 = make_float4(0.0f, 0.0f, 0.0f, 0.0f);
#pragma unroll
            for (int r = 0; r < 8; ++r) f[r] = z4;
#pragma unroll
            for (int i = 0; i < 4; ++i) hx[i] = 0.0f;
        }
    };
    auto stage_store = [&](int rx) {
        const int slot = (rx + 1) & 3;
        char* dbase = xs + slot * SLOT_B;
#pragma unroll
        for (int j = 0; j < 4; ++j) {
            union { __hip_bfloat16 u[8]; bf16x8 v; } pk;
#pragma unroll
            for (int r = 0; r < 8; ++r) {
                float v = (j == 0) ? f[r].x : (j == 1) ? f[r].y : (j == 2) ? f[r].z : f[r].w;
                pk.u[r] = __float2bfloat16(v);
            }
            int ww = 4 * q + 1 + j;          // 1..128
            *reinterpret_cast<bf16x8*>(dbase + swz(ww, cb)) = pk.v;
        }
        if (tid < 32) {
            union { __hip_bfloat16 u[4]; short4 v; } pk;
#pragma unroll
            for (int i = 0; i < 4; ++i) pk.u[i] = __float2bfloat16(hx[i]);
            int ww = hside ? (WTILE + 1) : 0;        // 129 or 0; (ww>>2)&7 == 0
            *reinterpret_cast<short4*>(dbase + swz(ww, hcb) + hhi * 8) = pk.v;
        }
    };

    auto barrier = [&]() {
        asm volatile("s_waitcnt lgkmcnt(0)" ::: "memory");
        __builtin_amdgcn_s_barrier();
    };

    // prologue: x rows h0-1, h0, h0+1 -> slots 0,1,2
    stage_load(-1); stage_store(-1);
    stage_load(0);  stage_store(0);
    stage_load(1);  stage_store(1);
    barrier();

    for (int st = 0; st < HSTRIP; ++st) {
        // 1. issue next row's global loads (land during compute)
        const bool do_stage = (st + 2 <= HSTRIP);
        if (do_stage) stage_load(st + 2);

        // 2. compute output row h0+st
        f32x16 a[2];
#pragma unroll
        for (int nf = 0; nf < 2; ++nf)
#pragma unroll
            for (int i = 0; i < 16; ++i) a[nf][i] = 0.0f;

#pragma unroll
        for (int s = 0; s < 36; ++s) {
            const int tap = s >> 2, cq = s & 3;
            const int dh = tap / 3, dw = tap % 3;
            const int slotbase = ((st + dh) & 3) * SLOT_B;
#pragma unroll
            for (int nf = 0; nf < 2; ++nf) {
                int ww = nh * 64 + nf * 32 + n + dw;                 // 0..129
                bf16x8 bf = *reinterpret_cast<const bf16x8*>(xs + slotbase + swz(ww, cq * 2 + half));
                a[nf] = __builtin_amdgcn_mfma_f32_32x32x16_bf16(wf[s], bf, a[nf], 0, 0, 0);
            }
        }

        // 3. cvt+pack staged row -> ring slot (st+3)&3. Wait-for-loads here
        //    only has the PREVIOUS iteration's out-stores ahead of it.
        if (do_stage) stage_store(st + 2);

        // 4. epilogue: direct global stores (never waited on this iteration).
        //    For fixed reg: lanes n=0..31 cover 128B contiguous at
        //    (o = mh*32 + 4*half + (r&3)+8*(r>>2), row hrow).
        {
            const int hrow = h0 + st;
            size_t base = ((size_t)(b * On + mh * 32 + 4 * half) * Hn + hrow) * Wn
                          + w0 + nh * 64 + n;
#pragma unroll
            for (int nf = 0; nf < 2; ++nf)
#pragma unroll
                for (int r = 0; r < 16; ++r) {
                    int o_off = (r & 3) + 8 * (r >> 2);
                    out[base + (size_t)o_off * HW + nf * 32] = a[nf][r];
                }
        }

        // 5. publish staged row / protect ring reuse (LDS-only fence + barrier;
        //    out-stores and next loads stay in flight)
        barrier();
    }
}

// ---------------------------------------------------------------------------
extern "C" void kernel_launch(void* const* d_in, const int* in_sizes, int n_in,
                              void* d_out, int out_size, void* d_ws, size_t ws_size,
                              hipStream_t stream)
{
    const float* x   = (const float*)d_in[0];
    const int*   sid = (const int*)d_in[1];
    const float* Wc  = (const float*)d_in[2];
    const float* Wa  = (const float*)d_in[3];
    const float* Wb  = (const float*)d_in[4];
    float*       out = (float*)d_out;

    __hip_bfloat16* Wfrag = (__hip_bfloat16*)d_ws;   // 294912 B, rewritten each call

    merge_k<<<En * 2 * 36 * 64 * 8 / 256, 256, 0, stream>>>(Wc, Wa, Wb, Wfrag);

    dim3 grid(Wn / WTILE, Hn / HSTRIP, Bn);
    conv5_k<<<grid, 256, 0, stream>>>(x, sid, Wfrag, out);
}